// Round 9
// baseline (19406.352 us; speedup 1.0000x reference)
//
#include <hip/hip_runtime.h>

#define VOCAB 32000
#define EMBD  512
#define HIDD  1024
#define SLEN  512
#define NBAT  4
#define GATE4 4096   // 4*HIDD
#define ABLK  128    // layer-0 blocks (8 units each)
#define BBLK  128    // layer-1 blocks (8 units each)

typedef unsigned long long u64;

// ---------------- embedding gather ----------------
__global__ void embed_k(const int* __restrict__ ids, const float* __restrict__ emb,
                        float* __restrict__ X0) {
  const int n  = blockIdx.x;             // 0..2047 (= b*SLEN + s)
  const int id = ids[n];
  ((float4*)X0)[(size_t)n*(EMBD/4) + threadIdx.x] =
      ((const float4*)emb)[(size_t)id*(EMBD/4) + threadIdx.x];
}

// ------- 32x32 tiled transpose with dst leading-dim/offset:
// src [1024][4096] row-major; dst[(col)][off + row], row stride ldd.
__global__ __launch_bounds__(256) void transpose_ld(const float* __restrict__ src,
                                                    float* __restrict__ dst,
                                                    int ldd, int off) {
  __shared__ float t[32][33];
  const int bx = blockIdx.x * 32;   // col base (0..4095)
  const int by = blockIdx.y * 32;   // row base (0..1023)
  const int r0 = threadIdx.x >> 5;  // 0..7
  const int c  = threadIdx.x & 31;
  #pragma unroll
  for (int i = 0; i < 4; i++) {
    const int r = r0 + i*8;
    t[r][c] = src[(size_t)(by + r)*GATE4 + bx + c];
  }
  __syncthreads();
  #pragma unroll
  for (int i = 0; i < 4; i++) {
    const int rw = r0 + i*8;
    dst[(size_t)(bx + rw)*ldd + off + by + c] = t[c][rw];
  }
}

// ---------------- f32 tiled GEMM: C = A@B + bias ----------------
__global__ __launch_bounds__(256) void gemm_nn_bias(
    const float* __restrict__ A, const float* __restrict__ B,
    const float* __restrict__ bias, float* __restrict__ C,
    int M, int N, int K) {
  __shared__ float As[16][64];
  __shared__ float Bs[16][64];
  const int tid = threadIdx.x;
  const int bm = blockIdx.y * 64;
  const int bn = blockIdx.x * 64;
  const int tx = tid & 15, ty = tid >> 4;
  const int mA = tid >> 2, kqA = (tid & 3) * 4;
  const int kB = tid >> 4, nB = (tid & 15) * 4;
  float acc[4][4] = {{0.f}};
  for (int k0 = 0; k0 < K; k0 += 16) {
    float4 a4 = *(const float4*)(A + (size_t)(bm + mA)*K + k0 + kqA);
    As[kqA+0][mA] = a4.x; As[kqA+1][mA] = a4.y;
    As[kqA+2][mA] = a4.z; As[kqA+3][mA] = a4.w;
    *(float4*)&Bs[kB][nB] = *(const float4*)(B + (size_t)(k0 + kB)*N + bn + nB);
    __syncthreads();
    #pragma unroll
    for (int k = 0; k < 16; k++) {
      float4 av = *(float4*)&As[k][ty*4];
      float4 bv = *(float4*)&Bs[k][tx*4];
      float ar[4] = {av.x, av.y, av.z, av.w};
      float br[4] = {bv.x, bv.y, bv.z, bv.w};
      #pragma unroll
      for (int i = 0; i < 4; i++)
        #pragma unroll
        for (int j = 0; j < 4; j++)
          acc[i][j] += ar[i] * br[j];
    }
    __syncthreads();
  }
  float4 bi = *(const float4*)(bias + bn + tx*4);
  #pragma unroll
  for (int i = 0; i < 4; i++) {
    float4 o;
    o.x = acc[i][0] + bi.x; o.y = acc[i][1] + bi.y;
    o.z = acc[i][2] + bi.z; o.w = acc[i][3] + bi.w;
    *(float4*)(C + (size_t)(bm + ty*4 + i)*N + bn + tx*4) = o;
  }
}

// ---------------- logits GEMM: C = A @ Bt^T, with pad-mask ----------------
__global__ __launch_bounds__(256) void gemm_nt_logits(
    const float* __restrict__ A,   // P [2048, 512] (in d_ws — must NOT alias C)
    const float* __restrict__ Bt,  // emb [32000, 512]
    const int* __restrict__ ids,   // [2048]
    float* __restrict__ C) {       // [2048, 32000]
  const int K = EMBD, N = VOCAB;
  __shared__ float As[16][64];
  __shared__ float Bs[16][64];
  const int tid = threadIdx.x;
  const int bm = blockIdx.y * 64;
  const int bn = blockIdx.x * 64;
  const int tx = tid & 15, ty = tid >> 4;
  const int rA = tid >> 2, kq = (tid & 3) * 4;
  float acc[4][4] = {{0.f}};
  for (int k0 = 0; k0 < K; k0 += 16) {
    float4 a4 = *(const float4*)(A  + (size_t)(bm + rA)*K + k0 + kq);
    float4 b4 = *(const float4*)(Bt + (size_t)(bn + rA)*K + k0 + kq);
    As[kq+0][rA] = a4.x; As[kq+1][rA] = a4.y; As[kq+2][rA] = a4.z; As[kq+3][rA] = a4.w;
    Bs[kq+0][rA] = b4.x; Bs[kq+1][rA] = b4.y; Bs[kq+2][rA] = b4.z; Bs[kq+3][rA] = b4.w;
    __syncthreads();
    #pragma unroll
    for (int k = 0; k < 16; k++) {
      float4 av = *(float4*)&As[k][ty*4];
      float4 bv = *(float4*)&Bs[k][tx*4];
      float ar[4] = {av.x, av.y, av.z, av.w};
      float br[4] = {bv.x, bv.y, bv.z, bv.w};
      #pragma unroll
      for (int i = 0; i < 4; i++)
        #pragma unroll
        for (int j = 0; j < 4; j++)
          acc[i][j] += ar[i] * br[j];
    }
    __syncthreads();
  }
  #pragma unroll
  for (int i = 0; i < 4; i++) {
    const int row = bm + ty*4 + i;
    const bool mk = ids[row] != 0;
    float4 o;
    if (mk) { o.x = acc[i][0]; o.y = acc[i][1]; o.z = acc[i][2]; o.w = acc[i][3]; }
    else    { o.x = (bn + tx*4 == 0) ? 1.f : 0.f; o.y = 0.f; o.z = 0.f; o.w = 0.f; }
    *(float4*)(C + (size_t)row*N + bn + tx*4) = o;
  }
}

// ---------------- fused 2-layer pipelined LSTM (512-thread blocks) ----------
// 256 blocks x 512 thr (8 waves, ~250 VGPR -> exactly 1 block/CU; no CU
// sharing, no co-residency requirement for correctness).
// A (0..127): layer-0, 8 units, K=1024, Wf=64 f32/thread. Free-runs on its
//   own chain (H0full write-once -> never waits on B). Publishes flgA=t+1.
// B (128..255): layer-1, 8 units, K=2048 fused GEMV over hc = h0(t)||h1(t-1)
//   with WcT=[Wk1;Wr1]^T; 128 f32/thread. One 32KB gather burst (h0 from
//   H0full, h1 straight from H1 rows). Joint parallel poll: lanes<128 watch
//   flgA, lanes 128..255 watch flgB. Publishes flgB=t+1.
// All data relaxed agent-scope atomics; flag after wave-0 s_waitcnt vmcnt(0).
__device__ __forceinline__ int rev5(int l) {
  return ((l & 1) << 4) | ((l & 2) << 2) | (l & 4) | ((l & 8) >> 2) | ((l & 16) >> 4);
}

#define HALVE(MASK, SH, HSZ)                          \
    { const int bit_ = (lane >> SH) & 1;              \
      _Pragma("unroll")                               \
      for (int j = 0; j < HSZ; j++) {                 \
        float snd = bit_ ? a[j] : a[j + HSZ];         \
        float kep = bit_ ? a[j + HSZ] : a[j];         \
        a[j] = kep + __shfl_xor(snd, MASK);           \
      } }

__global__ __launch_bounds__(512, 1) void lstm_fused(
    const float* __restrict__ Z0,     // [B*S, 4096] x@Wk0 + b0
    const float* __restrict__ Wr0T,   // [4096][1024]
    const float* __restrict__ WcT,    // [4096][2048] = [Wk1;Wr1]^T
    const float* __restrict__ bias1,  // [4096]
    const int* __restrict__ ids,      // [B*S]
    float* __restrict__ H1,           // [B*S, 1024] layer-1 h sequence
    float* __restrict__ H0full,       // [SLEN][4][1024] streamed h0
    unsigned* __restrict__ flgA,      // [128*16] (zeroed)
    unsigned* __restrict__ flgB) {    // [128*16] (zeroed)
  __shared__ float hc[NBAT * 2048];   // [b][2048]: h0 | h1 (A uses h0 half)
  __shared__ float z_s[8][64];
  __shared__ float zc[128];
  const int tid  = threadIdx.x;
  const int lane = tid & 63;
  const int w    = tid >> 6;
  const int ccH  = tid >> 8;          // 0..1 (which 16 of 32 gate cols)
  const int part = tid & 255;         // k-slice owner

  if (blockIdx.x < ABLK) {
    // ================= role A: layer-0 =================
    const int hbase = blockIdx.x * 8;
    float4 Wf[16];
    #pragma unroll
    for (int cl = 0; cl < 16; cl++) {
      const int cc = ccH * 16 + cl;
      const int g  = cc >> 3, d = cc & 7;
      Wf[cl] = *(const float4*)(Wr0T + (size_t)(g*HIDD + hbase + d)*HIDD + 4*part);
    }
    float c_reg = 0.f, h_reg = 0.f;
    for (int i = tid; i < NBAT * 2048; i += 512) hc[i] = 0.f;
    __syncthreads();

    for (int t = 0; t < SLEN; t++) {
      float pz0 = 0.f, pz1 = 0.f, pz2 = 0.f, pz3 = 0.f;
      int pmk = 0;
      if (tid < 32) {
        const int b = tid >> 3, d = tid & 7;
        const float* zrow = Z0 + (size_t)(b*SLEN + t) * GATE4 + hbase + d;
        pz0 = zrow[0];      pz1 = zrow[HIDD];
        pz2 = zrow[2*HIDD]; pz3 = zrow[3*HIDD];
        pmk = ids[b*SLEN + t];
      }
      if (t > 0) {
        if (tid < ABLK) {
          while (__hip_atomic_load(flgA + tid * 16, __ATOMIC_RELAXED,
                                   __HIP_MEMORY_SCOPE_AGENT) < (unsigned)t)
            __builtin_amdgcn_s_sleep(1);
        }
        __syncthreads();
        const u64* src = (const u64*)H0full + (size_t)(t - 1) * 2048;
        u64 v[4];
        #pragma unroll
        for (int r = 0; r < 4; r++) {
          const int j = tid + (r << 9), b = j >> 9, ku = j & 511;
          v[r] = __hip_atomic_load(src + b*512 + ku,
                                   __ATOMIC_RELAXED, __HIP_MEMORY_SCOPE_AGENT);
        }
        #pragma unroll
        for (int r = 0; r < 4; r++) {
          const int j = tid + (r << 9), b = j >> 9, ku = j & 511;
          ((u64*)hc)[b*1024 + ku] = v[r];
        }
        __syncthreads();
      }
      float4 ha[NBAT];
      #pragma unroll
      for (int b = 0; b < NBAT; b++)
        ha[b] = ((const float4*)(hc + b*2048))[part];
      float a[64];
      #pragma unroll
      for (int cl = 0; cl < 16; cl++)
        #pragma unroll
        for (int b = 0; b < NBAT; b++)
          a[cl*4 + b] = Wf[cl].x*ha[b].x + Wf[cl].y*ha[b].y
                      + Wf[cl].z*ha[b].z + Wf[cl].w*ha[b].w;
      #pragma unroll
      for (int i = 0; i < 64; i++) a[i] += __shfl_xor(a[i], 32);
      HALVE(1, 0, 32) HALVE(2, 1, 16) HALVE(4, 2, 8) HALVE(8, 3, 4) HALVE(16, 4, 2)
      if (lane < 32) {
        z_s[w][rev5(lane)*2 + 0] = a[0];
        z_s[w][rev5(lane)*2 + 1] = a[1];
      }
      __syncthreads();
      if (tid < 128) {  // sum 4 waves per ccH-half
        const int cc = tid >> 2, b = tid & 3;
        const int cH = cc >> 4, i = ((cc & 15) << 2) | b;
        zc[tid] = z_s[4*cH][i] + z_s[4*cH+1][i] + z_s[4*cH+2][i] + z_s[4*cH+3][i];
      }
      __syncthreads();
      if (tid < 32) {
        const int b = tid >> 3, d = tid & 7;
        const float zi = zc[((0*8 + d) << 2) + b] + pz0;
        const float zf = zc[((1*8 + d) << 2) + b] + pz1;
        const float zg = zc[((2*8 + d) << 2) + b] + pz2;
        const float zo = zc[((3*8 + d) << 2) + b] + pz3;
        const float ig = 1.f / (1.f + expf(-zi));
        const float fg = 1.f / (1.f + expf(-zf));
        const float gg = tanhf(zg);
        const float og = 1.f / (1.f + expf(-zo));
        const float cn = fg * c_reg + ig * gg;
        const float hn = og * tanhf(cn);
        const bool mk = pmk != 0;
        const float ho = mk ? hn : h_reg;
        c_reg = mk ? cn : c_reg;
        h_reg = ho;
        __hip_atomic_store(H0full + (size_t)t * (NBAT*HIDD) + b*HIDD + hbase + d,
                           ho, __ATOMIC_RELAXED, __HIP_MEMORY_SCOPE_AGENT);
      }
      if (w == 0) {
        asm volatile("s_waitcnt vmcnt(0)" ::: "memory");
        if (tid == 0)
          __hip_atomic_store(flgA + blockIdx.x * 16, (unsigned)(t + 1),
                             __ATOMIC_RELAXED, __HIP_MEMORY_SCOPE_AGENT);
      }
    }
  } else {
    // ================= role B: layer-1 (fused K=2048 GEMV) =================
    const int bid = blockIdx.x - ABLK;   // 0..127
    const int ub  = bid * 8;
    float4 Wf[16], Wg[16];
    #pragma unroll
    for (int cl = 0; cl < 16; cl++) {
      const int cc = ccH * 16 + cl;
      const int g  = cc >> 3, d = cc & 7;
      const float* wrow = WcT + (size_t)(g*HIDD + ub + d) * 2048 + 8*part;
      Wf[cl] = *(const float4*)(wrow);
      Wg[cl] = *(const float4*)(wrow + 4);
    }
    float pbi = 0.f, pbf = 0.f, pbg = 0.f, pbo = 0.f;
    if (tid < 32) {
      const int d = tid & 7;
      pbi = bias1[0*HIDD + ub + d];
      pbf = bias1[1*HIDD + ub + d];
      pbg = bias1[2*HIDD + ub + d];
      pbo = bias1[3*HIDD + ub + d];
    }
    float c_reg = 0.f, h_reg = 0.f;
    for (int i = tid; i < NBAT * 2048; i += 512) hc[i] = 0.f;
    __syncthreads();

    for (int t = 0; t < SLEN; t++) {
      int pmk = 0;
      if (tid < 32) pmk = ids[(tid >> 3) * SLEN + t];
      // joint parallel poll: lanes<128 watch flgA>=t+1, 128..255 watch flgB>=t
      if (tid < 128) {
        while (__hip_atomic_load(flgA + tid * 16, __ATOMIC_RELAXED,
                                 __HIP_MEMORY_SCOPE_AGENT) < (unsigned)(t + 1))
          __builtin_amdgcn_s_sleep(1);
      } else if (tid < 256) {
        while (__hip_atomic_load(flgB + (tid - 128) * 16, __ATOMIC_RELAXED,
                                 __HIP_MEMORY_SCOPE_AGENT) < (unsigned)t)
          __builtin_amdgcn_s_sleep(1);
      }
      __syncthreads();
      {  // one 32KB gather burst: hc = h0(t) || h1(t-1)
        const u64* h0p = (const u64*)H0full + (size_t)t * 2048;
        const u64* h1p = (const u64*)H1;
        u64 v[8];
        #pragma unroll
        for (int r = 0; r < 8; r++) {
          const int j = tid + (r << 9), b = j >> 10, ku = j & 1023;
          if (ku < 512) {
            v[r] = __hip_atomic_load(h0p + b*512 + ku,
                                     __ATOMIC_RELAXED, __HIP_MEMORY_SCOPE_AGENT);
          } else if (t > 0) {
            v[r] = __hip_atomic_load(h1p + ((size_t)(b*SLEN + t - 1))*512
                                         + (ku - 512),
                                     __ATOMIC_RELAXED, __HIP_MEMORY_SCOPE_AGENT);
          } else {
            v[r] = 0ull;
          }
        }
        #pragma unroll
        for (int r = 0; r < 8; r++)
          ((u64*)hc)[tid + (r << 9)] = v[r];
        __syncthreads();
      }
      float4 ha[NBAT], hb[NBAT];
      #pragma unroll
      for (int b = 0; b < NBAT; b++) {
        ha[b] = ((const float4*)(hc + b*2048))[2*part];
        hb[b] = ((const float4*)(hc + b*2048))[2*part + 1];
      }
      float a[64];
      #pragma unroll
      for (int cl = 0; cl < 16; cl++)
        #pragma unroll
        for (int b = 0; b < NBAT; b++)
          a[cl*4 + b] = Wf[cl].x*ha[b].x + Wf[cl].y*ha[b].y
                      + Wf[cl].z*ha[b].z + Wf[cl].w*ha[b].w
                      + Wg[cl].x*hb[b].x + Wg[cl].y*hb[b].y
                      + Wg[cl].z*hb[b].z + Wg[cl].w*hb[b].w;
      #pragma unroll
      for (int i = 0; i < 64; i++) a[i] += __shfl_xor(a[i], 32);
      HALVE(1, 0, 32) HALVE(2, 1, 16) HALVE(4, 2, 8) HALVE(8, 3, 4) HALVE(16, 4, 2)
      if (lane < 32) {
        z_s[w][rev5(lane)*2 + 0] = a[0];
        z_s[w][rev5(lane)*2 + 1] = a[1];
      }
      __syncthreads();
      if (tid < 128) {
        const int cc = tid >> 2, b = tid & 3;
        const int cH = cc >> 4, i = ((cc & 15) << 2) | b;
        zc[tid] = z_s[4*cH][i] + z_s[4*cH+1][i] + z_s[4*cH+2][i] + z_s[4*cH+3][i];
      }
      __syncthreads();
      if (tid < 32) {
        const int b = tid >> 3, d = tid & 7;
        const float zi = zc[((0*8 + d) << 2) + b] + pbi;
        const float zf = zc[((1*8 + d) << 2) + b] + pbf;
        const float zg = zc[((2*8 + d) << 2) + b] + pbg;
        const float zo = zc[((3*8 + d) << 2) + b] + pbo;
        const float ig = 1.f / (1.f + expf(-zi));
        const float fg = 1.f / (1.f + expf(-zf));
        const float gg = tanhf(zg);
        const float og = 1.f / (1.f + expf(-zo));
        const float cn = fg * c_reg + ig * gg;
        const float hn = og * tanhf(cn);
        const bool mk = pmk != 0;
        const float ho = mk ? hn : h_reg;
        c_reg = mk ? cn : c_reg;
        h_reg = ho;
        __hip_atomic_store(H1 + (size_t)(b*SLEN + t) * HIDD + ub + d,
                           ho, __ATOMIC_RELAXED, __HIP_MEMORY_SCOPE_AGENT);
      }
      if (w == 0) {
        asm volatile("s_waitcnt vmcnt(0)" ::: "memory");
        if (tid == 0)
          __hip_atomic_store(flgB + bid * 16, (unsigned)(t + 1),
                             __ATOMIC_RELAXED, __HIP_MEMORY_SCOPE_AGENT);
      }
    }
  }
}
#undef HALVE

extern "C" void kernel_launch(void* const* d_in, const int* in_sizes, int n_in,
                              void* d_out, int out_size, void* d_ws, size_t ws_size,
                              hipStream_t stream) {
  const int*   ids = (const int*)  d_in[0];
  const float* emb = (const float*)d_in[1];
  const float* Wk0 = (const float*)d_in[2];
  const float* Wr0 = (const float*)d_in[3];
  const float* b0  = (const float*)d_in[4];
  const float* Wk1 = (const float*)d_in[5];
  const float* Wr1 = (const float*)d_in[6];
  const float* b1  = (const float*)d_in[7];
  const float* Wp  = (const float*)d_in[8];
  const float* bp  = (const float*)d_in[9];
  float* out = (float*)d_out;

  // DEAD-before-logits intermediates in the head of d_out (all consumed
  // before gemm_nt_logits); flags + P in d_ws.
  float* X0     = out;                  // [2048,  512]  1,048,576 f
  float* Z      = out + 1048576;        // [2048, 4096]  8,388,608 f (L0)
  float* H1     = out + 9437184;        // [2048, 1024]  2,097,152 f
  float* Wr0T   = out + 11534336;       // [4096][1024]  4,194,304 f
  float* WcT    = out + 15728640;       // [4096][2048]  8,388,608 f
  float* H0full = out + 24117248;       // [512][4096]   2,097,152 f
  unsigned* flgA = (unsigned*)d_ws;              // [128*16] u32 = 8 KB
  unsigned* flgB = (unsigned*)d_ws + 2048;       // [128*16] u32 = 8 KB
  float* P   = ((float*)d_ws) + 4096;   // [2048, 512] 1,048,576 f = 4 MB

  hipMemsetAsync(d_ws, 0, 16384, stream);  // zero both flag arrays
  embed_k<<<2048, 128, 0, stream>>>(ids, emb, X0);
  transpose_ld<<<dim3(128, 32), 256, 0, stream>>>(Wr0, Wr0T, 1024, 0);
  transpose_ld<<<dim3(128, 32), 256, 0, stream>>>(Wk1, WcT, 2048, 0);
  transpose_ld<<<dim3(128, 32), 256, 0, stream>>>(Wr1, WcT, 2048, 1024);
  gemm_nn_bias<<<dim3(64, 32), 256, 0, stream>>>(X0, Wk0, b0, Z, 2048, 4096, 512);
  lstm_fused<<<ABLK + BBLK, 512, 0, stream>>>(Z, Wr0T, WcT, b1, ids,
                                              H1, H0full, flgA, flgB);
  gemm_nn_bias<<<dim3(8, 32), 256, 0, stream>>>(H1, Wp, bp, P, 2048, 512, 1024);
  gemm_nt_logits<<<dim3(500, 32), 256, 0, stream>>>(P, emb, ids, out);
}

// Round 10
// 6707.148 us; speedup vs baseline: 2.8934x; 2.8934x over previous
//
#include <hip/hip_runtime.h>

#define VOCAB 32000
#define EMBD  512
#define HIDD  1024
#define SLEN  512
#define NBAT  4
#define GATE4 4096   // 4*HIDD
#define ABLK  128    // layer-0 blocks, 8 units each
#define BBLK  256    // layer-1 blocks, 4 units each

typedef unsigned long long u64;

#define AL(p) __hip_atomic_load((p), __ATOMIC_RELAXED, __HIP_MEMORY_SCOPE_AGENT)
#define AS(p, v) __hip_atomic_store((p), (v), __ATOMIC_RELAXED, __HIP_MEMORY_SCOPE_AGENT)

__device__ __forceinline__ float2 u2f(u64 x) {
  return make_float2(__uint_as_float((unsigned)x),
                     __uint_as_float((unsigned)(x >> 32)));
}

// ---------------- embedding gather ----------------
__global__ void embed_k(const int* __restrict__ ids, const float* __restrict__ emb,
                        float* __restrict__ X0) {
  const int n  = blockIdx.x;             // 0..2047 (= b*SLEN + s)
  const int id = ids[n];
  ((float4*)X0)[(size_t)n*(EMBD/4) + threadIdx.x] =
      ((const float4*)emb)[(size_t)id*(EMBD/4) + threadIdx.x];
}

// ---------------- 32x32 tiled transpose: [1024][4096] -> [4096][1024] -------
__global__ __launch_bounds__(256) void transpose_k(const float* __restrict__ src,
                                                   float* __restrict__ dst) {
  __shared__ float t[32][33];
  const int bx = blockIdx.x * 32;
  const int by = blockIdx.y * 32;
  const int r0 = threadIdx.x >> 5;
  const int c  = threadIdx.x & 31;
  #pragma unroll
  for (int i = 0; i < 4; i++) {
    const int r = r0 + i*8;
    t[r][c] = src[(size_t)(by + r)*GATE4 + bx + c];
  }
  __syncthreads();
  #pragma unroll
  for (int i = 0; i < 4; i++) {
    const int rw = r0 + i*8;
    dst[(size_t)(bx + rw)*HIDD + by + c] = t[c][rw];
  }
}

// ---------------- f32 tiled GEMM: C = A@B + bias ----------------
__global__ __launch_bounds__(256) void gemm_nn_bias(
    const float* __restrict__ A, const float* __restrict__ B,
    const float* __restrict__ bias, float* __restrict__ C,
    int M, int N, int K) {
  __shared__ float As[16][64];
  __shared__ float Bs[16][64];
  const int tid = threadIdx.x;
  const int bm = blockIdx.y * 64;
  const int bn = blockIdx.x * 64;
  const int tx = tid & 15, ty = tid >> 4;
  const int mA = tid >> 2, kqA = (tid & 3) * 4;
  const int kB = tid >> 4, nB = (tid & 15) * 4;
  float acc[4][4] = {{0.f}};
  for (int k0 = 0; k0 < K; k0 += 16) {
    float4 a4 = *(const float4*)(A + (size_t)(bm + mA)*K + k0 + kqA);
    As[kqA+0][mA] = a4.x; As[kqA+1][mA] = a4.y;
    As[kqA+2][mA] = a4.z; As[kqA+3][mA] = a4.w;
    *(float4*)&Bs[kB][nB] = *(const float4*)(B + (size_t)(k0 + kB)*N + bn + nB);
    __syncthreads();
    #pragma unroll
    for (int k = 0; k < 16; k++) {
      float4 av = *(float4*)&As[k][ty*4];
      float4 bv = *(float4*)&Bs[k][tx*4];
      float ar[4] = {av.x, av.y, av.z, av.w};
      float br[4] = {bv.x, bv.y, bv.z, bv.w};
      #pragma unroll
      for (int i = 0; i < 4; i++)
        #pragma unroll
        for (int j = 0; j < 4; j++)
          acc[i][j] += ar[i] * br[j];
    }
    __syncthreads();
  }
  float4 bi = *(const float4*)(bias + bn + tx*4);
  #pragma unroll
  for (int i = 0; i < 4; i++) {
    float4 o;
    o.x = acc[i][0] + bi.x; o.y = acc[i][1] + bi.y;
    o.z = acc[i][2] + bi.z; o.w = acc[i][3] + bi.w;
    *(float4*)(C + (size_t)(bm + ty*4 + i)*N + bn + tx*4) = o;
  }
}

// ---------------- logits GEMM: C = A @ Bt^T, with pad-mask ----------------
__global__ __launch_bounds__(256) void gemm_nt_logits(
    const float* __restrict__ A,   // P [2048, 512] (in d_ws — must NOT alias C)
    const float* __restrict__ Bt,  // emb [32000, 512]
    const int* __restrict__ ids,   // [2048]
    float* __restrict__ C) {       // [2048, 32000]
  const int K = EMBD, N = VOCAB;
  __shared__ float As[16][64];
  __shared__ float Bs[16][64];
  const int tid = threadIdx.x;
  const int bm = blockIdx.y * 64;
  const int bn = blockIdx.x * 64;
  const int tx = tid & 15, ty = tid >> 4;
  const int rA = tid >> 2, kq = (tid & 3) * 4;
  float acc[4][4] = {{0.f}};
  for (int k0 = 0; k0 < K; k0 += 16) {
    float4 a4 = *(const float4*)(A  + (size_t)(bm + rA)*K + k0 + kq);
    float4 b4 = *(const float4*)(Bt + (size_t)(bn + rA)*K + k0 + kq);
    As[kq+0][rA] = a4.x; As[kq+1][rA] = a4.y; As[kq+2][rA] = a4.z; As[kq+3][rA] = a4.w;
    Bs[kq+0][rA] = b4.x; Bs[kq+1][rA] = b4.y; Bs[kq+2][rA] = b4.z; Bs[kq+3][rA] = b4.w;
    __syncthreads();
    #pragma unroll
    for (int k = 0; k < 16; k++) {
      float4 av = *(float4*)&As[k][ty*4];
      float4 bv = *(float4*)&Bs[k][tx*4];
      float ar[4] = {av.x, av.y, av.z, av.w};
      float br[4] = {bv.x, bv.y, bv.z, bv.w};
      #pragma unroll
      for (int i = 0; i < 4; i++)
        #pragma unroll
        for (int j = 0; j < 4; j++)
          acc[i][j] += ar[i] * br[j];
    }
    __syncthreads();
  }
  #pragma unroll
  for (int i = 0; i < 4; i++) {
    const int row = bm + ty*4 + i;
    const bool mk = ids[row] != 0;
    float4 o;
    if (mk) { o.x = acc[i][0]; o.y = acc[i][1]; o.z = acc[i][2]; o.w = acc[i][3]; }
    else    { o.x = (bn + tx*4 == 0) ? 1.f : 0.f; o.y = 0.f; o.z = 0.f; o.w = 0.f; }
    *(float4*)(C + (size_t)row*N + bn + tx*4) = o;
  }
}

// ---------------- fused 2-layer pipelined LSTM recurrence -------------------
// 384 blocks x 256 thr, launch_bounds(256,1) -> 256 VGPR (the ONLY config
// verified not to cap/spill; rounds 7/9 showed (256,2) and (512,1) cap at 128).
// A (0..127): layer-0, 8 units; streams h0(t) into H0full[t] (write-once, so
//   A never waits on B; dep graph A->A, A->B, B->B acyclic in any schedule).
// B (128..383): layer-1, 4 units; z1 = Wk1T*h0(t) + Wr1T*h1(t-1) + b1; h1
//   read directly from H1 rows (Hx1 eliminated).
// Exchange: PARALLEL poll phase (disjoint lanes watch disjoint flags), then
// per-thread direct u64 relaxed-atomic gather into registers (no LDS staging,
// no extra barriers). Flags stored by wave 0 after s_waitcnt vmcnt(0).
__device__ __forceinline__ int rev5(int l) {
  return ((l & 1) << 4) | ((l & 2) << 2) | (l & 4) | ((l & 8) >> 2) | ((l & 16) >> 4);
}

#define HALVE(MASK, SH, HSZ)                          \
    { const int bit_ = (lane >> SH) & 1;              \
      _Pragma("unroll")                               \
      for (int j = 0; j < HSZ; j++) {                 \
        float snd = bit_ ? a[j] : a[j + HSZ];         \
        float kep = bit_ ? a[j + HSZ] : a[j];         \
        a[j] = kep + __shfl_xor(snd, MASK);           \
      } }

__global__ __launch_bounds__(256, 1) void lstm_fused(
    const float* __restrict__ Z0,     // [B*S, 4096] x@Wk0 + b0
    const float* __restrict__ Wr0T,   // [4096][1024]
    const float* __restrict__ Wk1T,   // [4096][1024]
    const float* __restrict__ Wr1T,   // [4096][1024]
    const float* __restrict__ bias1,  // [4096]
    const int* __restrict__ ids,      // [B*S]
    float* __restrict__ H1,           // [B*S, 1024] layer-1 h sequence
    float* __restrict__ H0full,       // [SLEN][4][1024] streamed h0
    unsigned* __restrict__ flgA,      // [128*16] (zeroed)
    unsigned* __restrict__ flgB) {    // [256*16] (zeroed)
  __shared__ float z_s[4][64];
  __shared__ float zc[128];
  const int tid  = threadIdx.x;
  const int lane = tid & 63;
  const int w    = tid >> 6;
  const int ccH  = tid >> 7;
  const int part = tid & 127;

  if (blockIdx.x < ABLK) {
    // ================= role A: layer-0, 8 units =================
    const int hbase = blockIdx.x * 8;
    float4 Wf[16], Wg[16];
    #pragma unroll
    for (int cl = 0; cl < 16; cl++) {
      const int cc = ccH * 16 + cl;
      const int g  = cc >> 3, d = cc & 7;
      const size_t col = (size_t)(g * HIDD + hbase + d);
      Wf[cl] = *(const float4*)(Wr0T + col * HIDD + 4 * part);
      Wg[cl] = *(const float4*)(Wr0T + col * HIDD + 512 + 4 * part);
    }
    float c_reg = 0.f, h_reg = 0.f;
    __syncthreads();

    for (int t = 0; t < SLEN; t++) {
      float pz0 = 0.f, pz1 = 0.f, pz2 = 0.f, pz3 = 0.f;
      int pmk = 0;
      if (tid < 32) {
        const int b = tid >> 3, d = tid & 7;
        const float* zrow = Z0 + (size_t)(b*SLEN + t) * GATE4 + hbase + d;
        pz0 = zrow[0];      pz1 = zrow[HIDD];
        pz2 = zrow[2*HIDD]; pz3 = zrow[3*HIDD];
        pmk = ids[b*SLEN + t];
      }
      float4 ha[NBAT], hb[NBAT];
      if (t > 0) {
        if (tid < ABLK) {
          while (AL(flgA + tid * 16) < (unsigned)t)
            __builtin_amdgcn_s_sleep(1);
        }
        __syncthreads();
        // direct per-thread gather of h0(t-1): 16 u64 -> registers
        const u64* src = (const u64*)H0full + (size_t)(t - 1) * 2048;
        u64 v[16];
        #pragma unroll
        for (int b = 0; b < NBAT; b++) {
          v[b*4+0] = AL(src + b*512 + 2*part);
          v[b*4+1] = AL(src + b*512 + 2*part + 1);
          v[b*4+2] = AL(src + b*512 + 256 + 2*part);
          v[b*4+3] = AL(src + b*512 + 256 + 2*part + 1);
        }
        #pragma unroll
        for (int b = 0; b < NBAT; b++) {
          float2 p0 = u2f(v[b*4+0]), p1 = u2f(v[b*4+1]);
          float2 q0 = u2f(v[b*4+2]), q1 = u2f(v[b*4+3]);
          ha[b] = make_float4(p0.x, p0.y, p1.x, p1.y);
          hb[b] = make_float4(q0.x, q0.y, q1.x, q1.y);
        }
      } else {
        #pragma unroll
        for (int b = 0; b < NBAT; b++) {
          ha[b] = make_float4(0.f, 0.f, 0.f, 0.f);
          hb[b] = make_float4(0.f, 0.f, 0.f, 0.f);
        }
      }
      float a[64];
      #pragma unroll
      for (int cl = 0; cl < 16; cl++)
        #pragma unroll
        for (int b = 0; b < NBAT; b++)
          a[cl*4 + b] = Wf[cl].x*ha[b].x + Wf[cl].y*ha[b].y
                      + Wf[cl].z*ha[b].z + Wf[cl].w*ha[b].w
                      + Wg[cl].x*hb[b].x + Wg[cl].y*hb[b].y
                      + Wg[cl].z*hb[b].z + Wg[cl].w*hb[b].w;
      #pragma unroll
      for (int i = 0; i < 64; i++) a[i] += __shfl_xor(a[i], 32);
      HALVE(1, 0, 32) HALVE(2, 1, 16) HALVE(4, 2, 8) HALVE(8, 3, 4) HALVE(16, 4, 2)
      if (lane < 32) {
        z_s[w][rev5(lane)*2 + 0] = a[0];
        z_s[w][rev5(lane)*2 + 1] = a[1];
      }
      __syncthreads();
      if (tid < 128) {
        const int cc = tid >> 2, b = tid & 3;
        const int cH = cc >> 4, i = ((cc & 15) << 2) | b;
        zc[tid] = z_s[2*cH][i] + z_s[2*cH + 1][i];
      }
      __syncthreads();
      if (tid < 32) {
        const int b = tid >> 3, d = tid & 7;
        const float zi = zc[((0*8 + d) << 2) + b] + pz0;
        const float zf = zc[((1*8 + d) << 2) + b] + pz1;
        const float zg = zc[((2*8 + d) << 2) + b] + pz2;
        const float zo = zc[((3*8 + d) << 2) + b] + pz3;
        const float ig = 1.f / (1.f + expf(-zi));
        const float fg = 1.f / (1.f + expf(-zf));
        const float gg = tanhf(zg);
        const float og = 1.f / (1.f + expf(-zo));
        const float cn = fg * c_reg + ig * gg;
        const float hn = og * tanhf(cn);
        const bool mk = pmk != 0;
        const float ho = mk ? hn : h_reg;
        c_reg = mk ? cn : c_reg;
        h_reg = ho;
        AS(H0full + (size_t)t * (NBAT*HIDD) + b*HIDD + hbase + d, ho);
      }
      if (w == 0) {
        asm volatile("s_waitcnt vmcnt(0)" ::: "memory");
        if (tid == 0)
          AS(flgA + blockIdx.x * 16, (unsigned)(t + 1));
      }
      __syncthreads();  // z_s/zc reuse safety for next iter
    }
  } else {
    // ================= role B: layer-1, 4 units =================
    const int bid = blockIdx.x - ABLK;     // 0..255
    const int ub  = bid * 4;
    float4 Kf[8], Kg[8], Rf[8], Rg[8];
    #pragma unroll
    for (int cl = 0; cl < 8; cl++) {
      const int cc = ccH * 8 + cl;
      const int g  = cc >> 2, u = cc & 3;
      const size_t col = (size_t)(g * HIDD + ub + u);
      Kf[cl] = *(const float4*)(Wk1T + col * HIDD + 4 * part);
      Kg[cl] = *(const float4*)(Wk1T + col * HIDD + 512 + 4 * part);
      Rf[cl] = *(const float4*)(Wr1T + col * HIDD + 4 * part);
      Rg[cl] = *(const float4*)(Wr1T + col * HIDD + 512 + 4 * part);
    }
    float pbi = 0.f, pbf = 0.f, pbg = 0.f, pbo = 0.f;
    if (tid < 16) {
      const int u = tid & 3;
      pbi = bias1[0*HIDD + ub + u];
      pbf = bias1[1*HIDD + ub + u];
      pbg = bias1[2*HIDD + ub + u];
      pbo = bias1[3*HIDD + ub + u];
    }
    float c_reg = 0.f, h_reg = 0.f;
    __syncthreads();

    for (int t = 0; t < SLEN; t++) {
      int pmk = 0;
      if (tid < 16) pmk = ids[(tid >> 2) * SLEN + t];
      // ---- parallel poll: lanes<128 watch flgA; lanes 128.255 watch flgB x2
      if (tid < 128) {
        while (AL(flgA + tid * 16) < (unsigned)(t + 1))
          __builtin_amdgcn_s_sleep(1);
      } else if (t > 0) {
        const int f1 = tid - 128, f2 = tid;   // flgB indices (0..127, 128..255)
        unsigned a1 = AL(flgB + f1 * 16), a2 = AL(flgB + f2 * 16);
        while (a1 < (unsigned)t || a2 < (unsigned)t) {
          __builtin_amdgcn_s_sleep(1);
          if (a1 < (unsigned)t) a1 = AL(flgB + f1 * 16);
          if (a2 < (unsigned)t) a2 = AL(flgB + f2 * 16);
        }
      }
      __syncthreads();
      // ---- direct per-thread gather: h0(t) and h1(t-1), 32 u64 -> regs ----
      float4 xa[NBAT], xb[NBAT], ya[NBAT], yb[NBAT];
      {
        const u64* h0p = (const u64*)H0full + (size_t)t * 2048;
        u64 v0[16];
        #pragma unroll
        for (int b = 0; b < NBAT; b++) {
          v0[b*4+0] = AL(h0p + b*512 + 2*part);
          v0[b*4+1] = AL(h0p + b*512 + 2*part + 1);
          v0[b*4+2] = AL(h0p + b*512 + 256 + 2*part);
          v0[b*4+3] = AL(h0p + b*512 + 256 + 2*part + 1);
        }
        if (t > 0) {
          const u64* h1p = (const u64*)H1;
          u64 v1[16];
          #pragma unroll
          for (int b = 0; b < NBAT; b++) {
            const size_t row = (size_t)(b*SLEN + t - 1) * 512;
            v1[b*4+0] = AL(h1p + row + 2*part);
            v1[b*4+1] = AL(h1p + row + 2*part + 1);
            v1[b*4+2] = AL(h1p + row + 256 + 2*part);
            v1[b*4+3] = AL(h1p + row + 256 + 2*part + 1);
          }
          #pragma unroll
          for (int b = 0; b < NBAT; b++) {
            float2 p0 = u2f(v1[b*4+0]), p1 = u2f(v1[b*4+1]);
            float2 q0 = u2f(v1[b*4+2]), q1 = u2f(v1[b*4+3]);
            ya[b] = make_float4(p0.x, p0.y, p1.x, p1.y);
            yb[b] = make_float4(q0.x, q0.y, q1.x, q1.y);
          }
        } else {
          #pragma unroll
          for (int b = 0; b < NBAT; b++) {
            ya[b] = make_float4(0.f, 0.f, 0.f, 0.f);
            yb[b] = make_float4(0.f, 0.f, 0.f, 0.f);
          }
        }
        #pragma unroll
        for (int b = 0; b < NBAT; b++) {
          float2 p0 = u2f(v0[b*4+0]), p1 = u2f(v0[b*4+1]);
          float2 q0 = u2f(v0[b*4+2]), q1 = u2f(v0[b*4+3]);
          xa[b] = make_float4(p0.x, p0.y, p1.x, p1.y);
          xb[b] = make_float4(q0.x, q0.y, q1.x, q1.y);
        }
      }
      float a[32];
      #pragma unroll
      for (int cl = 0; cl < 8; cl++)
        #pragma unroll
        for (int b = 0; b < NBAT; b++)
          a[cl*4 + b] = Kf[cl].x*xa[b].x + Kf[cl].y*xa[b].y
                      + Kf[cl].z*xa[b].z + Kf[cl].w*xa[b].w
                      + Kg[cl].x*xb[b].x + Kg[cl].y*xb[b].y
                      + Kg[cl].z*xb[b].z + Kg[cl].w*xb[b].w
                      + Rf[cl].x*ya[b].x + Rf[cl].y*ya[b].y
                      + Rf[cl].z*ya[b].z + Rf[cl].w*ya[b].w
                      + Rg[cl].x*yb[b].x + Rg[cl].y*yb[b].y
                      + Rg[cl].z*yb[b].z + Rg[cl].w*yb[b].w;
      #pragma unroll
      for (int i = 0; i < 32; i++) a[i] += __shfl_xor(a[i], 32);
      HALVE(1, 0, 16) HALVE(2, 1, 8) HALVE(4, 2, 4) HALVE(8, 3, 2) HALVE(16, 4, 1)
      if (lane < 32) z_s[w][rev5(lane)] = a[0];
      __syncthreads();
      if (tid < 64) {
        const int h_ = tid >> 5, i5 = tid & 31;
        zc[tid] = z_s[2*h_][i5] + z_s[2*h_ + 1][i5];
      }
      __syncthreads();
      if (tid < 16) {
        const int b = tid >> 2, u = tid & 3;
        const float zi = zc[      u      * 4 + b] + pbi;
        const float zf = zc[     (4 + u) * 4 + b] + pbf;
        const float zg = zc[32 +  u      * 4 + b] + pbg;
        const float zo = zc[32 + (4 + u) * 4 + b] + pbo;
        const float ig = 1.f / (1.f + expf(-zi));
        const float fg = 1.f / (1.f + expf(-zf));
        const float gg = tanhf(zg);
        const float og = 1.f / (1.f + expf(-zo));
        const float cn = fg * c_reg + ig * gg;
        const float hn = og * tanhf(cn);
        const bool mk = pmk != 0;
        const float ho = mk ? hn : h_reg;
        c_reg = mk ? cn : c_reg;
        h_reg = ho;
        AS(H1 + (size_t)(b*SLEN + t) * HIDD + ub + u, ho);
      }
      if (w == 0) {
        asm volatile("s_waitcnt vmcnt(0)" ::: "memory");
        if (tid == 0)
          AS(flgB + bid * 16, (unsigned)(t + 1));
      }
      __syncthreads();  // z_s/zc reuse safety for next iter
    }
  }
}
#undef HALVE

extern "C" void kernel_launch(void* const* d_in, const int* in_sizes, int n_in,
                              void* d_out, int out_size, void* d_ws, size_t ws_size,
                              hipStream_t stream) {
  const int*   ids = (const int*)  d_in[0];
  const float* emb = (const float*)d_in[1];
  const float* Wk0 = (const float*)d_in[2];
  const float* Wr0 = (const float*)d_in[3];
  const float* b0  = (const float*)d_in[4];
  const float* Wk1 = (const float*)d_in[5];
  const float* Wr1 = (const float*)d_in[6];
  const float* b1  = (const float*)d_in[7];
  const float* Wp  = (const float*)d_in[8];
  const float* bp  = (const float*)d_in[9];
  float* out = (float*)d_out;

  // DEAD-before-logits intermediates in the head of d_out; cross-kernel live
  // data (flags, P) in d_ws.
  float* X0     = out;                  // [2048,  512]  1,048,576 f
  float* Z      = out + 1048576;        // [2048, 4096]  8,388,608 f (L0)
  float* H1     = out + 9437184;        // [2048, 1024]  2,097,152 f
  float* Wr0T   = out + 11534336;       // [4096][1024]  4,194,304 f
  float* Wr1T   = out + 15728640;       // [4096][1024]  4,194,304 f
  float* Wk1T   = out + 19922944;       // [4096][1024]  4,194,304 f
  float* H0full = out + 24117248;       // [512][4096]   2,097,152 f
  unsigned* flgA = (unsigned*)d_ws;              // [128*16] u32 = 8 KB
  unsigned* flgB = (unsigned*)d_ws + 2048;       // [256*16] u32 = 16 KB
  float* P   = ((float*)d_ws) + 6144;   // [2048, 512] 1,048,576 f = 4 MB

  hipMemsetAsync(d_ws, 0, 24576, stream);  // zero both flag arrays
  embed_k<<<2048, 128, 0, stream>>>(ids, emb, X0);
  transpose_k<<<dim3(128, 32), 256, 0, stream>>>(Wr0, Wr0T);
  transpose_k<<<dim3(128, 32), 256, 0, stream>>>(Wr1, Wr1T);
  transpose_k<<<dim3(128, 32), 256, 0, stream>>>(Wk1, Wk1T);
  gemm_nn_bias<<<dim3(64, 32), 256, 0, stream>>>(X0, Wk0, b0, Z, 2048, 4096, 512);
  lstm_fused<<<ABLK + BBLK, 256, 0, stream>>>(Z, Wr0T, Wk1T, Wr1T, b1, ids,
                                              H1, H0full, flgA, flgB);
  gemm_nn_bias<<<dim3(8, 32), 256, 0, stream>>>(H1, Wp, bp, P, 2048, 512, 1024);
  gemm_nt_logits<<<dim3(500, 32), 256, 0, stream>>>(P, emb, ids, out);
}

// Round 11
// 4999.740 us; speedup vs baseline: 3.8815x; 1.3415x over previous
//
#include <hip/hip_runtime.h>

#define VOCAB 32000
#define EMBD  512
#define HIDD  1024
#define SLEN  512
#define NBAT  4
#define GATE4 4096   // 4*HIDD
#define ABLK  128    // layer-0 blocks, 8 units each
#define BBLK  128    // layer-1 blocks, 8 units each (Wk1 in LDS, Wr1 in regs)

typedef unsigned long long u64;

#define AL(p) __hip_atomic_load((p), __ATOMIC_RELAXED, __HIP_MEMORY_SCOPE_AGENT)
#define AS(p, v) __hip_atomic_store((p), (v), __ATOMIC_RELAXED, __HIP_MEMORY_SCOPE_AGENT)

__device__ __forceinline__ float2 u2f(u64 x) {
  return make_float2(__uint_as_float((unsigned)x),
                     __uint_as_float((unsigned)(x >> 32)));
}

// ---------------- embedding gather ----------------
__global__ void embed_k(const int* __restrict__ ids, const float* __restrict__ emb,
                        float* __restrict__ X0) {
  const int n  = blockIdx.x;             // 0..2047 (= b*SLEN + s)
  const int id = ids[n];
  ((float4*)X0)[(size_t)n*(EMBD/4) + threadIdx.x] =
      ((const float4*)emb)[(size_t)id*(EMBD/4) + threadIdx.x];
}

// ---------------- 32x32 tiled transpose: [1024][4096] -> [4096][1024] -------
__global__ __launch_bounds__(256) void transpose_k(const float* __restrict__ src,
                                                   float* __restrict__ dst) {
  __shared__ float t[32][33];
  const int bx = blockIdx.x * 32;
  const int by = blockIdx.y * 32;
  const int r0 = threadIdx.x >> 5;
  const int c  = threadIdx.x & 31;
  #pragma unroll
  for (int i = 0; i < 4; i++) {
    const int r = r0 + i*8;
    t[r][c] = src[(size_t)(by + r)*GATE4 + bx + c];
  }
  __syncthreads();
  #pragma unroll
  for (int i = 0; i < 4; i++) {
    const int rw = r0 + i*8;
    dst[(size_t)(bx + rw)*HIDD + by + c] = t[c][rw];
  }
}

// ---------------- f32 tiled GEMM: C = A@B + bias ----------------
__global__ __launch_bounds__(256) void gemm_nn_bias(
    const float* __restrict__ A, const float* __restrict__ B,
    const float* __restrict__ bias, float* __restrict__ C,
    int M, int N, int K) {
  __shared__ float As[16][64];
  __shared__ float Bs[16][64];
  const int tid = threadIdx.x;
  const int bm = blockIdx.y * 64;
  const int bn = blockIdx.x * 64;
  const int tx = tid & 15, ty = tid >> 4;
  const int mA = tid >> 2, kqA = (tid & 3) * 4;
  const int kB = tid >> 4, nB = (tid & 15) * 4;
  float acc[4][4] = {{0.f}};
  for (int k0 = 0; k0 < K; k0 += 16) {
    float4 a4 = *(const float4*)(A + (size_t)(bm + mA)*K + k0 + kqA);
    As[kqA+0][mA] = a4.x; As[kqA+1][mA] = a4.y;
    As[kqA+2][mA] = a4.z; As[kqA+3][mA] = a4.w;
    *(float4*)&Bs[kB][nB] = *(const float4*)(B + (size_t)(k0 + kB)*N + bn + nB);
    __syncthreads();
    #pragma unroll
    for (int k = 0; k < 16; k++) {
      float4 av = *(float4*)&As[k][ty*4];
      float4 bv = *(float4*)&Bs[k][tx*4];
      float ar[4] = {av.x, av.y, av.z, av.w};
      float br[4] = {bv.x, bv.y, bv.z, bv.w};
      #pragma unroll
      for (int i = 0; i < 4; i++)
        #pragma unroll
        for (int j = 0; j < 4; j++)
          acc[i][j] += ar[i] * br[j];
    }
    __syncthreads();
  }
  float4 bi = *(const float4*)(bias + bn + tx*4);
  #pragma unroll
  for (int i = 0; i < 4; i++) {
    float4 o;
    o.x = acc[i][0] + bi.x; o.y = acc[i][1] + bi.y;
    o.z = acc[i][2] + bi.z; o.w = acc[i][3] + bi.w;
    *(float4*)(C + (size_t)(bm + ty*4 + i)*N + bn + tx*4) = o;
  }
}

// ---------------- logits GEMM: C = A @ Bt^T, with pad-mask ----------------
__global__ __launch_bounds__(256) void gemm_nt_logits(
    const float* __restrict__ A,   // P [2048, 512] (in d_ws — must NOT alias C)
    const float* __restrict__ Bt,  // emb [32000, 512]
    const int* __restrict__ ids,   // [2048]
    float* __restrict__ C) {       // [2048, 32000]
  const int K = EMBD, N = VOCAB;
  __shared__ float As[16][64];
  __shared__ float Bs[16][64];
  const int tid = threadIdx.x;
  const int bm = blockIdx.y * 64;
  const int bn = blockIdx.x * 64;
  const int tx = tid & 15, ty = tid >> 4;
  const int rA = tid >> 2, kq = (tid & 3) * 4;
  float acc[4][4] = {{0.f}};
  for (int k0 = 0; k0 < K; k0 += 16) {
    float4 a4 = *(const float4*)(A  + (size_t)(bm + rA)*K + k0 + kq);
    float4 b4 = *(const float4*)(Bt + (size_t)(bn + rA)*K + k0 + kq);
    As[kq+0][rA] = a4.x; As[kq+1][rA] = a4.y; As[kq+2][rA] = a4.z; As[kq+3][rA] = a4.w;
    Bs[kq+0][rA] = b4.x; Bs[kq+1][rA] = b4.y; Bs[kq+2][rA] = b4.z; Bs[kq+3][rA] = b4.w;
    __syncthreads();
    #pragma unroll
    for (int k = 0; k < 16; k++) {
      float4 av = *(float4*)&As[k][ty*4];
      float4 bv = *(float4*)&Bs[k][tx*4];
      float ar[4] = {av.x, av.y, av.z, av.w};
      float br[4] = {bv.x, bv.y, bv.z, bv.w};
      #pragma unroll
      for (int i = 0; i < 4; i++)
        #pragma unroll
        for (int j = 0; j < 4; j++)
          acc[i][j] += ar[i] * br[j];
    }
    __syncthreads();
  }
  #pragma unroll
  for (int i = 0; i < 4; i++) {
    const int row = bm + ty*4 + i;
    const bool mk = ids[row] != 0;
    float4 o;
    if (mk) { o.x = acc[i][0]; o.y = acc[i][1]; o.z = acc[i][2]; o.w = acc[i][3]; }
    else    { o.x = (bn + tx*4 == 0) ? 1.f : 0.f; o.y = 0.f; o.z = 0.f; o.w = 0.f; }
    *(float4*)(C + (size_t)row*N + bn + tx*4) = o;
  }
}

// ---------------- fused 2-layer pipelined LSTM recurrence -------------------
// 256 blocks x 256 thr, launch_bounds(256,1) [the only config proven to give
// the full 256-VGPR budget; (256,2) and (512,1) cap at 128 and spill].
// A (0..127): layer-0, 8 units, Wr0 in 128 VGPRs; streams h0(t) -> H0full[t]
//   (write-once buffer: A depends only on A; A-blocks dispatch first =>
//   guaranteed progress in any schedule).
// B (128..255): layer-1, 8 units; Wr1 in 128 VGPRs, Wk1 in 128 KB LDS.
//   z1 = Wk1T(LDS)*h0(t) + Wr1T(regs)*h1(t-1) + b1, two register passes.
//   h1 exchange directly through H1 rows. Fan-in: 128 flgA (passes instantly,
//   A runs ahead) + 128 flgB. Publishers per role: 128 (round-6 economics).
// All exchange relaxed agent-scope atomics; flag stored by wave 0 after
// s_waitcnt vmcnt(0). 130 KB LDS -> 1 block/CU.
__device__ __forceinline__ int rev5(int l) {
  return ((l & 1) << 4) | ((l & 2) << 2) | (l & 4) | ((l & 8) >> 2) | ((l & 16) >> 4);
}

#define HALVE(MASK, SH, HSZ)                          \
    { const int bit_ = (lane >> SH) & 1;              \
      _Pragma("unroll")                               \
      for (int j = 0; j < HSZ; j++) {                 \
        float snd = bit_ ? a[j] : a[j + HSZ];         \
        float kep = bit_ ? a[j + HSZ] : a[j];         \
        a[j] = kep + __shfl_xor(snd, MASK);           \
      } }

__global__ __launch_bounds__(256, 1) void lstm_fused(
    const float* __restrict__ Z0,     // [B*S, 4096] x@Wk0 + b0
    const float* __restrict__ Wr0T,   // [4096][1024]
    const float* __restrict__ Wk1T,   // [4096][1024]
    const float* __restrict__ Wr1T,   // [4096][1024]
    const float* __restrict__ bias1,  // [4096]
    const int* __restrict__ ids,      // [B*S]
    float* __restrict__ H1,           // [B*S, 1024] layer-1 h sequence
    float* __restrict__ H0full,       // [SLEN][4][1024] streamed h0
    unsigned* __restrict__ flgA,      // [128*16] (zeroed)
    unsigned* __restrict__ flgB) {    // [128*16] (zeroed)
  __shared__ float wk[32][1024];      // B only: Wk1 cols (128 KB)
  __shared__ float z_s[4][64];
  __shared__ float zc[128];
  const int tid  = threadIdx.x;
  const int lane = tid & 63;
  const int w    = tid >> 6;
  const int ccH  = tid >> 7;          // 0..1 (which 16 of the 32 gate cols)
  const int part = tid & 127;         // k-slice owner (8 k values per matrix)

  if (blockIdx.x < ABLK) {
    // ================= role A: layer-0, 8 units =================
    const int hbase = blockIdx.x * 8;
    float4 Wf[16], Wg[16];
    #pragma unroll
    for (int cl = 0; cl < 16; cl++) {
      const int cc = ccH * 16 + cl;
      const int g  = cc >> 3, d = cc & 7;
      const size_t col = (size_t)(g * HIDD + hbase + d);
      Wf[cl] = *(const float4*)(Wr0T + col * HIDD + 4 * part);
      Wg[cl] = *(const float4*)(Wr0T + col * HIDD + 512 + 4 * part);
    }
    float c_reg = 0.f, h_reg = 0.f;
    __syncthreads();

    for (int t = 0; t < SLEN; t++) {
      float pz0 = 0.f, pz1 = 0.f, pz2 = 0.f, pz3 = 0.f;
      int pmk = 0;
      if (tid < 32) {
        const int b = tid >> 3, d = tid & 7;
        const float* zrow = Z0 + (size_t)(b*SLEN + t) * GATE4 + hbase + d;
        pz0 = zrow[0];      pz1 = zrow[HIDD];
        pz2 = zrow[2*HIDD]; pz3 = zrow[3*HIDD];
        pmk = ids[b*SLEN + t];
      }
      float4 ha[NBAT], hb[NBAT];
      if (t > 0) {
        if (tid < ABLK) {
          while (AL(flgA + tid * 16) < (unsigned)t)
            __builtin_amdgcn_s_sleep(1);
        }
        __syncthreads();
        const u64* src = (const u64*)H0full + (size_t)(t - 1) * 2048;
        u64 v[16];
        #pragma unroll
        for (int b = 0; b < NBAT; b++) {
          v[b*4+0] = AL(src + b*512 + 2*part);
          v[b*4+1] = AL(src + b*512 + 2*part + 1);
          v[b*4+2] = AL(src + b*512 + 256 + 2*part);
          v[b*4+3] = AL(src + b*512 + 256 + 2*part + 1);
        }
        #pragma unroll
        for (int b = 0; b < NBAT; b++) {
          float2 p0 = u2f(v[b*4+0]), p1 = u2f(v[b*4+1]);
          float2 q0 = u2f(v[b*4+2]), q1 = u2f(v[b*4+3]);
          ha[b] = make_float4(p0.x, p0.y, p1.x, p1.y);
          hb[b] = make_float4(q0.x, q0.y, q1.x, q1.y);
        }
      } else {
        #pragma unroll
        for (int b = 0; b < NBAT; b++) {
          ha[b] = make_float4(0.f, 0.f, 0.f, 0.f);
          hb[b] = make_float4(0.f, 0.f, 0.f, 0.f);
        }
      }
      float a[64];
      #pragma unroll
      for (int cl = 0; cl < 16; cl++)
        #pragma unroll
        for (int b = 0; b < NBAT; b++)
          a[cl*4 + b] = Wf[cl].x*ha[b].x + Wf[cl].y*ha[b].y
                      + Wf[cl].z*ha[b].z + Wf[cl].w*ha[b].w
                      + Wg[cl].x*hb[b].x + Wg[cl].y*hb[b].y
                      + Wg[cl].z*hb[b].z + Wg[cl].w*hb[b].w;
      #pragma unroll
      for (int i = 0; i < 64; i++) a[i] += __shfl_xor(a[i], 32);
      HALVE(1, 0, 32) HALVE(2, 1, 16) HALVE(4, 2, 8) HALVE(8, 3, 4) HALVE(16, 4, 2)
      if (lane < 32) {
        z_s[w][rev5(lane)*2 + 0] = a[0];
        z_s[w][rev5(lane)*2 + 1] = a[1];
      }
      __syncthreads();
      if (tid < 128) {
        const int cc = tid >> 2, b = tid & 3;
        const int cH = cc >> 4, i = ((cc & 15) << 2) | b;
        zc[tid] = z_s[2*cH][i] + z_s[2*cH + 1][i];
      }
      __syncthreads();
      if (tid < 32) {
        const int b = tid >> 3, d = tid & 7;
        const float zi = zc[((0*8 + d) << 2) + b] + pz0;
        const float zf = zc[((1*8 + d) << 2) + b] + pz1;
        const float zg = zc[((2*8 + d) << 2) + b] + pz2;
        const float zo = zc[((3*8 + d) << 2) + b] + pz3;
        const float ig = 1.f / (1.f + expf(-zi));
        const float fg = 1.f / (1.f + expf(-zf));
        const float gg = tanhf(zg);
        const float og = 1.f / (1.f + expf(-zo));
        const float cn = fg * c_reg + ig * gg;
        const float hn = og * tanhf(cn);
        const bool mk = pmk != 0;
        const float ho = mk ? hn : h_reg;
        c_reg = mk ? cn : c_reg;
        h_reg = ho;
        AS(H0full + (size_t)t * (NBAT*HIDD) + b*HIDD + hbase + d, ho);
      }
      if (w == 0) {
        asm volatile("s_waitcnt vmcnt(0)" ::: "memory");
        if (tid == 0)
          AS(flgA + blockIdx.x * 16, (unsigned)(t + 1));
      }
      __syncthreads();  // z_s/zc reuse safety
    }
  } else {
    // ================= role B: layer-1, 8 units =================
    const int bid = blockIdx.x - ABLK;   // 0..127
    const int ub  = bid * 8;
    // stage this block's 32 Wk1 columns into LDS (128 KB), coalesced
    for (int i = tid; i < 32 * 256; i += 256) {
      const int c2 = i >> 8, k4 = i & 255;
      const size_t col = (size_t)((c2 >> 3) * HIDD + ub + (c2 & 7));
      *(float4*)&wk[c2][k4 * 4] = *(const float4*)(Wk1T + col * HIDD + 4 * k4);
    }
    float4 Rf[16], Rg[16];
    #pragma unroll
    for (int cl = 0; cl < 16; cl++) {
      const int cc = ccH * 16 + cl;
      const int g  = cc >> 3, d = cc & 7;
      const size_t col = (size_t)(g * HIDD + ub + d);
      Rf[cl] = *(const float4*)(Wr1T + col * HIDD + 4 * part);
      Rg[cl] = *(const float4*)(Wr1T + col * HIDD + 512 + 4 * part);
    }
    float pbi = 0.f, pbf = 0.f, pbg = 0.f, pbo = 0.f;
    if (tid < 32) {
      const int d = tid & 7;
      pbi = bias1[0*HIDD + ub + d];
      pbf = bias1[1*HIDD + ub + d];
      pbg = bias1[2*HIDD + ub + d];
      pbo = bias1[3*HIDD + ub + d];
    }
    float c_reg = 0.f, h_reg = 0.f;
    __syncthreads();   // wk ready

    for (int t = 0; t < SLEN; t++) {
      int pmk = 0;
      if (tid < 32) pmk = ids[(tid >> 3) * SLEN + t];
      // parallel poll: lanes<128 watch flgA>=t+1; lanes 128..255 watch flgB>=t
      if (tid < 128) {
        while (AL(flgA + tid * 16) < (unsigned)(t + 1))
          __builtin_amdgcn_s_sleep(1);
      } else {
        while (AL(flgB + (tid - 128) * 16) < (unsigned)t)
          __builtin_amdgcn_s_sleep(1);
      }
      __syncthreads();
      // gather h0(t) and h1(t-1) straight into registers (u64 = 2 floats)
      const u64* h0p = (const u64*)H0full + (size_t)t * 2048;
      u64 v0[16];
      #pragma unroll
      for (int b = 0; b < NBAT; b++) {
        v0[b*4+0] = AL(h0p + b*512 + 2*part);
        v0[b*4+1] = AL(h0p + b*512 + 2*part + 1);
        v0[b*4+2] = AL(h0p + b*512 + 256 + 2*part);
        v0[b*4+3] = AL(h0p + b*512 + 256 + 2*part + 1);
      }
      u64 v1[16];
      if (t > 0) {
        const u64* h1p = (const u64*)H1;
        #pragma unroll
        for (int b = 0; b < NBAT; b++) {
          const size_t row = (size_t)(b*SLEN + t - 1) * 512;
          v1[b*4+0] = AL(h1p + row + 2*part);
          v1[b*4+1] = AL(h1p + row + 2*part + 1);
          v1[b*4+2] = AL(h1p + row + 256 + 2*part);
          v1[b*4+3] = AL(h1p + row + 256 + 2*part + 1);
        }
      } else {
        #pragma unroll
        for (int r = 0; r < 16; r++) v1[r] = 0ull;
      }
      // pass 1: z = Wk1(LDS) . h0(t)
      float a[64];
      #pragma unroll
      for (int cl = 0; cl < 16; cl++) {
        const int c2 = ccH * 16 + cl;
        const float4 kf = *(const float4*)&wk[c2][4 * part];
        const float4 kg = *(const float4*)&wk[c2][512 + 4 * part];
        #pragma unroll
        for (int b = 0; b < NBAT; b++) {
          const float2 p0 = u2f(v0[b*4+0]), p1 = u2f(v0[b*4+1]);
          const float2 q0 = u2f(v0[b*4+2]), q1 = u2f(v0[b*4+3]);
          a[cl*4 + b] = kf.x*p0.x + kf.y*p0.y + kf.z*p1.x + kf.w*p1.y
                      + kg.x*q0.x + kg.y*q0.y + kg.z*q1.x + kg.w*q1.y;
        }
      }
      // pass 2: z += Wr1(regs) . h1(t-1)
      #pragma unroll
      for (int cl = 0; cl < 16; cl++) {
        #pragma unroll
        for (int b = 0; b < NBAT; b++) {
          const float2 p0 = u2f(v1[b*4+0]), p1 = u2f(v1[b*4+1]);
          const float2 q0 = u2f(v1[b*4+2]), q1 = u2f(v1[b*4+3]);
          a[cl*4 + b] += Rf[cl].x*p0.x + Rf[cl].y*p0.y + Rf[cl].z*p1.x + Rf[cl].w*p1.y
                       + Rg[cl].x*q0.x + Rg[cl].y*q0.y + Rg[cl].z*q1.x + Rg[cl].w*q1.y;
        }
      }
      #pragma unroll
      for (int i = 0; i < 64; i++) a[i] += __shfl_xor(a[i], 32);
      HALVE(1, 0, 32) HALVE(2, 1, 16) HALVE(4, 2, 8) HALVE(8, 3, 4) HALVE(16, 4, 2)
      if (lane < 32) {
        z_s[w][rev5(lane)*2 + 0] = a[0];
        z_s[w][rev5(lane)*2 + 1] = a[1];
      }
      __syncthreads();
      if (tid < 128) {
        const int cc = tid >> 2, b = tid & 3;
        const int cH = cc >> 4, i = ((cc & 15) << 2) | b;
        zc[tid] = z_s[2*cH][i] + z_s[2*cH + 1][i];
      }
      __syncthreads();
      if (tid < 32) {
        const int b = tid >> 3, d = tid & 7;
        const float zi = zc[((0*8 + d) << 2) + b] + pbi;
        const float zf = zc[((1*8 + d) << 2) + b] + pbf;
        const float zg = zc[((2*8 + d) << 2) + b] + pbg;
        const float zo = zc[((3*8 + d) << 2) + b] + pbo;
        const float ig = 1.f / (1.f + expf(-zi));
        const float fg = 1.f / (1.f + expf(-zf));
        const float gg = tanhf(zg);
        const float og = 1.f / (1.f + expf(-zo));
        const float cn = fg * c_reg + ig * gg;
        const float hn = og * tanhf(cn);
        const bool mk = pmk != 0;
        const float ho = mk ? hn : h_reg;
        c_reg = mk ? cn : c_reg;
        h_reg = ho;
        AS(H1 + (size_t)(b*SLEN + t) * HIDD + ub + d, ho);
      }
      if (w == 0) {
        asm volatile("s_waitcnt vmcnt(0)" ::: "memory");
        if (tid == 0)
          AS(flgB + bid * 16, (unsigned)(t + 1));
      }
      __syncthreads();  // z_s/zc reuse safety
    }
  }
}
#undef HALVE

extern "C" void kernel_launch(void* const* d_in, const int* in_sizes, int n_in,
                              void* d_out, int out_size, void* d_ws, size_t ws_size,
                              hipStream_t stream) {
  const int*   ids = (const int*)  d_in[0];
  const float* emb = (const float*)d_in[1];
  const float* Wk0 = (const float*)d_in[2];
  const float* Wr0 = (const float*)d_in[3];
  const float* b0  = (const float*)d_in[4];
  const float* Wk1 = (const float*)d_in[5];
  const float* Wr1 = (const float*)d_in[6];
  const float* b1  = (const float*)d_in[7];
  const float* Wp  = (const float*)d_in[8];
  const float* bp  = (const float*)d_in[9];
  float* out = (float*)d_out;

  // DEAD-before-logits intermediates in the head of d_out; cross-kernel live
  // data (flags, P) in d_ws.
  float* X0     = out;                  // [2048,  512]  1,048,576 f
  float* Z      = out + 1048576;        // [2048, 4096]  8,388,608 f (L0)
  float* H1     = out + 9437184;        // [2048, 1024]  2,097,152 f
  float* Wr0T   = out + 11534336;       // [4096][1024]  4,194,304 f
  float* Wr1T   = out + 15728640;       // [4096][1024]  4,194,304 f
  float* Wk1T   = out + 19922944;       // [4096][1024]  4,194,304 f
  float* H0full = out + 24117248;       // [512][4096]   2,097,152 f
  unsigned* flgA = (unsigned*)d_ws;              // [128*16] u32 = 8 KB
  unsigned* flgB = (unsigned*)d_ws + 2048;       // [128*16] u32 = 8 KB
  float* P   = ((float*)d_ws) + 4096;   // [2048, 512] 1,048,576 f = 4 MB

  hipMemsetAsync(d_ws, 0, 16384, stream);  // zero both flag arrays
  embed_k<<<2048, 128, 0, stream>>>(ids, emb, X0);
  transpose_k<<<dim3(128, 32), 256, 0, stream>>>(Wr0, Wr0T);
  transpose_k<<<dim3(128, 32), 256, 0, stream>>>(Wr1, Wr1T);
  transpose_k<<<dim3(128, 32), 256, 0, stream>>>(Wk1, Wk1T);
  gemm_nn_bias<<<dim3(64, 32), 256, 0, stream>>>(X0, Wk0, b0, Z, 2048, 4096, 512);
  lstm_fused<<<ABLK + BBLK, 256, 0, stream>>>(Z, Wr0T, Wk1T, Wr1T, b1, ids,
                                              H1, H0full, flgA, flgB);
  gemm_nn_bias<<<dim3(8, 32), 256, 0, stream>>>(H1, Wp, bp, P, 2048, 512, 1024);
  gemm_nt_logits<<<dim3(500, 32), 256, 0, stream>>>(P, emb, ids, out);
}